// Round 3
// baseline (283.687 us; speedup 1.0000x reference)
//
#include <hip/hip_runtime.h>
#include <hip/hip_bf16.h>

#define BB 512
#define TT 4096
#define EPSF 1e-5f

typedef __attribute__((ext_vector_type(8))) short bf16x8;  // 8 bf16 (4 VGPRs)
typedef __attribute__((ext_vector_type(4))) float f32x4;   // MFMA C/D

__device__ __forceinline__ unsigned pkbf(float lo, float hi) {
    __hip_bfloat162 h = __float22bfloat162_rn(make_float2(lo, hi));
    return *reinterpret_cast<unsigned*>(&h);
}
__device__ __forceinline__ short b16(float f) {
    __hip_bfloat16 h = __float2bfloat16(f);
    return *reinterpret_cast<short*>(&h);
}

#define XPITCH 48                    // 16 bf16 (32B) padded to 48B
#define XROWS  258
#define XSZ    (XROWS * XPITCH)      // 12384 B
#define HPITCH 80                    // 32 bf16 (64B) padded to 80B
#define LDS_SZ (XSZ + 4 * 16 * HPITCH)  // 12384 + 5120 = 17504 B

__global__ __launch_bounds__(256) void bimanual_fused2_kernel(
    const float* __restrict__ x,       // (B,T,16)
    const float* __restrict__ conv_w,  // (16,8,3)
    const float* __restrict__ conv_b,  // (16,)
    const float* __restrict__ w1,      // (32,16)
    const float* __restrict__ b1,      // (16,)
    const float* __restrict__ w2,      // (16,2)
    const float* __restrict__ b2,      // (2,)
    const float* __restrict__ ln_g,    // (16,)
    const float* __restrict__ ln_b,    // (16,)
    float* __restrict__ out)           // out_X (B*T*16) then alphas (B*T*2)
{
    __shared__ __align__(16) unsigned char lds[LDS_SZ];

    const int tid  = threadIdx.x;
    const int lane = tid & 63;
    const int w    = tid >> 6;        // wave id: positions [64w, 64w+64)
    const int c    = lane & 15;       // MFMA: A-row / B-col / D-col
    const int g    = lane >> 4;       // MFMA: k-group / D row-group
    const int p0   = blockIdx.x << 8;

    unsigned char* Hb = lds + XSZ + w * (16 * HPITCH);  // per-wave H scratch

    // ---- weight fragments (A-operands: M = out-feature, K via g*8+j) ----
    bf16x8 Wc, W1;
#pragma unroll
    for (int j = 0; j < 8; ++j) {
        const float wc = (g < 3) ? conv_w[(c * 8 + j) * 3 + g] : 0.f;  // A[och=c][k=g*8+j]
        Wc[j] = b16(wc);
        W1[j] = b16(w1[(g * 8 + j) * 16 + c]);                         // A[h=c][k=feat]
    }
    const float4 bc4 = *reinterpret_cast<const float4*>(conv_b + 4 * g);  // conv_b[4g+q]
    const float4 b14 = *reinterpret_cast<const float4*>(b1 + 4 * g);      // b1[4g+q]
    const float4 w2a = reinterpret_cast<const float4*>(w2)[2 * g];        // w2 rows 4g,4g+1
    const float4 w2b = reinterpret_cast<const float4*>(w2)[2 * g + 1];    // w2 rows 4g+2,4g+3

    // ---- phase 1: own row -> regs (exact f32) + bf16 -> LDS row tid+2 ----
    const size_t rowbase = (size_t)(p0 + tid) * 16;
    float xv[16];
    {
        const float4* xp = reinterpret_cast<const float4*>(x + rowbase);
#pragma unroll
        for (int k = 0; k < 4; ++k) {
            float4 v = xp[k];
            xv[4 * k] = v.x; xv[4 * k + 1] = v.y; xv[4 * k + 2] = v.z; xv[4 * k + 3] = v.w;
        }
        unsigned u[8];
#pragma unroll
        for (int k = 0; k < 8; ++k) u[k] = pkbf(xv[2 * k], xv[2 * k + 1]);
        *reinterpret_cast<uint4*>(lds + (tid + 2) * XPITCH)      = make_uint4(u[0], u[1], u[2], u[3]);
        *reinterpret_cast<uint4*>(lds + (tid + 2) * XPITCH + 16) = make_uint4(u[4], u[5], u[6], u[7]);
    }
    if (tid < 2) {  // halo rows 0,1 = global rows p0-2, p0-1 (zero at t==0)
        const bool tz = ((blockIdx.x & 15) == 0);
        unsigned u[8];
        if (tz) {
#pragma unroll
            for (int k = 0; k < 8; ++k) u[k] = 0u;
        } else {
            const float4* hp = reinterpret_cast<const float4*>(x + (size_t)(p0 - 2 + tid) * 16);
            float f[16];
#pragma unroll
            for (int k = 0; k < 4; ++k) {
                float4 v = hp[k];
                f[4 * k] = v.x; f[4 * k + 1] = v.y; f[4 * k + 2] = v.z; f[4 * k + 3] = v.w;
            }
#pragma unroll
            for (int k = 0; k < 8; ++k) u[k] = pkbf(f[2 * k], f[2 * k + 1]);
        }
        *reinterpret_cast<uint4*>(lds + tid * XPITCH)      = make_uint4(u[0], u[1], u[2], u[3]);
        *reinterpret_cast<uint4*>(lds + tid * XPITCH + 16) = make_uint4(u[4], u[5], u[6], u[7]);
    }
    __syncthreads();

    // ---- fused conv + dense1 + dense2 + softmax, per 16-pos tile m ----
    const bf16x8 zf = {0, 0, 0, 0, 0, 0, 0, 0};
    float a0own = 0.f, a1own = 0.f;
#pragma unroll
    for (int m = 0; m < 4; ++m) {
        const int posm = (w << 6) + (m << 4);
        // conv B-frag: col=pos (c), k-group g = tap -> X row posm+c+g, 8 ch contiguous
        const int arow = posm + c + ((g < 3) ? g : 0);
        bf16x8 XL = *reinterpret_cast<const bf16x8*>(lds + arow * XPITCH);
        bf16x8 XR = *reinterpret_cast<const bf16x8*>(lds + arow * XPITCH + 16);
        if (g == 3) { XL = zf; XR = zf; }
        f32x4 accL = {bc4.x, bc4.y, bc4.z, bc4.w};
        f32x4 accR = accL;
        accL = __builtin_amdgcn_mfma_f32_16x16x32_bf16(Wc, XL, accL, 0, 0, 0);
        accR = __builtin_amdgcn_mfma_f32_16x16x32_bf16(Wc, XR, accR, 0, 0, 0);
        // lane holds H[posm+c][och 4g+q] (L) and [16+4g+q] (R): consecutive feats -> b64 writes
        const unsigned pl0 = pkbf(fmaxf(accL[0], 0.f), fmaxf(accL[1], 0.f));
        const unsigned pl1 = pkbf(fmaxf(accL[2], 0.f), fmaxf(accL[3], 0.f));
        const unsigned pr0 = pkbf(fmaxf(accR[0], 0.f), fmaxf(accR[1], 0.f));
        const unsigned pr1 = pkbf(fmaxf(accR[2], 0.f), fmaxf(accR[3], 0.f));
        *reinterpret_cast<uint2*>(Hb + c * HPITCH + g * 8)      = make_uint2(pl0, pl1);
        *reinterpret_cast<uint2*>(Hb + c * HPITCH + 32 + g * 8) = make_uint2(pr0, pr1);
        // dense1 B-frag: col=pos (c), k = feat 8g..8g+7 (same-wave LDS, no barrier)
        bf16x8 Hf = *reinterpret_cast<const bf16x8*>(Hb + c * HPITCH + g * 16);
        f32x4 acc1 = {b14.x, b14.y, b14.z, b14.w};
        acc1 = __builtin_amdgcn_mfma_f32_16x16x32_bf16(W1, Hf, acc1, 0, 0, 0);
        // lane holds hidden[posm+c][h=4g+q] -> dense2 partials + cross-g reduce
        const float h0 = fmaxf(acc1[0], 0.f), h1 = fmaxf(acc1[1], 0.f);
        const float h2 = fmaxf(acc1[2], 0.f), h3 = fmaxf(acc1[3], 0.f);
        float l0 = h0 * w2a.x + h1 * w2a.z + h2 * w2b.x + h3 * w2b.z;
        float l1 = h0 * w2a.y + h1 * w2a.w + h2 * w2b.y + h3 * w2b.w;
        l0 += __shfl_xor(l0, 16); l0 += __shfl_xor(l0, 32);
        l1 += __shfl_xor(l1, 16); l1 += __shfl_xor(l1, 32);
        if (g == m) {  // this lane IS thread p0+tid's position for tile m
            l0 += b2[0]; l1 += b2[1];
            const float mm = fmaxf(l0, l1);
            const float e0 = __expf(l0 - mm);
            const float e1 = __expf(l1 - mm);
            const float inv = 1.f / (e0 + e1);
            a0own = e0 * inv;
            a1own = e1 * inv;
        }
    }

    // ---- epilogue: gated residual + LayerNorm (exact f32 x from regs) ----
    float y[16];
    const float g0 = 1.f + a0own;
    const float g1 = 1.f + a1own;
#pragma unroll
    for (int i = 0; i < 8; ++i) y[i] = xv[i] * g0;
#pragma unroll
    for (int i = 0; i < 8; ++i) y[8 + i] = xv[8 + i] * g1;

    float s = 0.f;
#pragma unroll
    for (int i = 0; i < 16; ++i) s += y[i];
    const float mu = s * (1.f / 16.f);
    float var = 0.f;
#pragma unroll
    for (int i = 0; i < 16; ++i) {
        const float d = y[i] - mu;
        var = fmaf(d, d, var);
    }
    const float rs = rsqrtf(var * (1.f / 16.f) + EPSF);

    float4* od = reinterpret_cast<float4*>(out + rowbase);
#pragma unroll
    for (int k = 0; k < 4; ++k) {
        float o0 = fmaf((y[4 * k]     - mu) * rs, ln_g[4 * k],     ln_b[4 * k]);
        float o1 = fmaf((y[4 * k + 1] - mu) * rs, ln_g[4 * k + 1], ln_b[4 * k + 1]);
        float o2 = fmaf((y[4 * k + 2] - mu) * rs, ln_g[4 * k + 2], ln_b[4 * k + 2]);
        float o3 = fmaf((y[4 * k + 3] - mu) * rs, ln_g[4 * k + 3], ln_b[4 * k + 3]);
        od[k] = make_float4(o0, o1, o2, o3);
    }
    *reinterpret_cast<float2*>(out + (size_t)BB * TT * 16 + (size_t)(p0 + tid) * 2)
        = make_float2(a0own, a1own);
}

extern "C" void kernel_launch(void* const* d_in, const int* in_sizes, int n_in,
                              void* d_out, int out_size, void* d_ws, size_t ws_size,
                              hipStream_t stream) {
    const float* x      = (const float*)d_in[0];
    const float* conv_w = (const float*)d_in[1];
    const float* conv_b = (const float*)d_in[2];
    const float* w1     = (const float*)d_in[3];
    const float* b1     = (const float*)d_in[4];
    const float* w2     = (const float*)d_in[5];
    const float* b2     = (const float*)d_in[6];
    const float* ln_g   = (const float*)d_in[7];
    const float* ln_b   = (const float*)d_in[8];
    float* out = (float*)d_out;

    const int total = BB * TT;
    dim3 block(256);
    dim3 grid(total / 256);
    hipLaunchKernelGGL(bimanual_fused2_kernel, grid, block, 0, stream,
                       x, conv_w, conv_b, w1, b1, w2, b2, ln_g, ln_b, out);
}